// Round 10
// baseline (656.886 us; speedup 1.0000x reference)
//
#include <hip/hip_runtime.h>
#include <math.h>

#define N_NODES 102400
#define N_EDGES 1638400
#define G_GRAPHS 256
#define NODES_PER_G 400
#define CAPB 7168          // per-graph edge bucket capacity (mean 6400, +9.6 sigma)
#define F_IN  64
#define H1    4
#define C1    32
#define F_MID 128
#define C2    32
#define CLIN  5
#define NEG   0.2f

__device__ __forceinline__ float lrelu(float x) { return x > 0.f ? x : NEG * x; }
__device__ __forceinline__ float elu(float x)   { return x > 0.f ? x : expm1f(x); }

// round-to-nearest-even fp32 -> bf16 (as ushort)
__device__ __forceinline__ unsigned short f2bf(float f) {
    unsigned u = __float_as_uint(f);
    u = (u + 0x7fffu + ((u >> 16) & 1u)) >> 16;
    return (unsigned short)u;
}
__device__ __forceinline__ float bfLO(unsigned p) { return __uint_as_float(p << 16); }
__device__ __forceinline__ float bfHI(unsigned p) { return __uint_as_float(p & 0xffff0000u); }
// unpack 4 bf16 (uint2) -> float4
__device__ __forceinline__ float4 bf2f4(uint2 p) {
    return make_float4(__uint_as_float(p.x << 16), __uint_as_float(p.x & 0xffff0000u),
                       __uint_as_float(p.y << 16), __uint_as_float(p.y & 0xffff0000u));
}

// ---------------- CSR build, LDS-binned (no global random atomics) ----------------
__global__ __launch_bounds__(256) void bin_k(const int* __restrict__ ei,
                                             int* __restrict__ gcnt,
                                             unsigned* __restrict__ binned) {
    __shared__ int hist[256];
    __shared__ int off[256];
    int t = threadIdx.x;
    hist[t] = 0;
    __syncthreads();
    int i0 = blockIdx.x * 4096;
#pragma unroll
    for (int j = 0; j < 16; ++j) {
        int d = ei[N_EDGES + i0 + j * 256 + t];
        atomicAdd(&hist[d / NODES_PER_G], 1);
    }
    __syncthreads();
    off[t] = atomicAdd(&gcnt[t], hist[t]);
    hist[t] = 0;                         // reuse as per-bucket running slot
    __syncthreads();
#pragma unroll
    for (int j = 0; j < 16; ++j) {
        int idx = i0 + j * 256 + t;
        int s = ei[idx];
        int d = ei[N_EDGES + idx];
        int g = d / NODES_PER_G;
        int dl = d - g * NODES_PER_G;
        int slot = atomicAdd(&hist[g], 1);
        binned[(size_t)g * CAPB + off[g] + slot] = (unsigned)s | ((unsigned)dl << 17);
    }
}

__global__ __launch_bounds__(512) void build_k(
    const int* __restrict__ gcnt, unsigned* __restrict__ binned,
    int* __restrict__ row_ptr, int* __restrict__ row_end)
{
    __shared__ unsigned edg[CAPB];
    __shared__ int coll[CAPB];
    __shared__ int hist[512];
    __shared__ int cur[NODES_PER_G];
    int g = blockIdx.x, t = threadIdx.x;
    int ne = gcnt[g];
    size_t base = (size_t)g * CAPB;
    for (int i = t; i < ne; i += 512) edg[i] = binned[base + i];
    hist[t] = 0;
    __syncthreads();
    for (int i = t; i < ne; i += 512) atomicAdd(&hist[edg[i] >> 17], 1);
    __syncthreads();
    int v = hist[t];
    for (int off = 1; off < 512; off <<= 1) {
        int tmp = (t >= off) ? hist[t - off] : 0;
        __syncthreads();
        hist[t] += tmp;
        __syncthreads();
    }
    int excl = hist[t] - v;
    if (t < NODES_PER_G) {
        cur[t] = excl;
        row_ptr[g * NODES_PER_G + t] = (int)base + excl;
    }
    __syncthreads();
    for (int i = t; i < ne; i += 512) {
        unsigned e = edg[i];
        int pos = atomicAdd(&cur[e >> 17], 1);
        coll[pos] = (int)(e & 0x1FFFFu);
    }
    __syncthreads();
    if (t < NODES_PER_G) row_end[g * NODES_PER_G + t] = (int)base + cur[t];
    for (int i = t; i < ne; i += 512) binned[base + i] = (unsigned)coll[i];
}

// ---- ht_k: h~ = x @ W1 (fp32 accum) -> bf16 table, HEAD-MAJOR [4][N][32ch]
//            + layer-1 logits split: als1 (src), ald1 (dst)
// Register-blocked: 64 nodes/block, 2 nodes/thread x 16 outs.
__global__ __launch_bounds__(256) void ht_k(
    const float* __restrict__ x, const float* __restrict__ W1,
    const float* __restrict__ a_src1, const float* __restrict__ a_dst1,
    unsigned short* __restrict__ hth, float* __restrict__ als1, float* __restrict__ ald1,
    float* __restrict__ pooled)
{
    __shared__ float xs[64 * 68];      // stride 68: 16B-aligned, ==4 mod 32
    __shared__ float W1s[64 * 160];    // skewed: k*160 + (c0>>4)*20 + (c0&15)
    int t = threadIdx.x;
    int n0 = blockIdx.x * 64;
    if (blockIdx.x == 0) {
        for (int j = t; j < G_GRAPHS * C2; j += 256) pooled[j] = 0.f;
    }
#pragma unroll
    for (int j = 0; j < 4; ++j) {
        int q = t + 256 * j;              // 1024 float4 over 64x64
        int n = q >> 4, c0 = (q & 15) * 4;
        *(float4*)&xs[n * 68 + c0] = ((const float4*)x)[(size_t)n0 * 16 + q];
    }
#pragma unroll
    for (int j = 0; j < 8; ++j) {
        int q = t + 256 * j;              // 2048 float4 over 64x128
        int k = q >> 5, c0 = (q & 31) * 4;
        float4 v = ((const float4*)W1)[q];
        *(float4*)&W1s[k * 160 + (c0 >> 4) * 20 + (c0 & 15)] = v;
    }
    __syncthreads();
    int np = t >> 3;                      // node pair 0..31
    int nA = 2 * np, nB = nA + 1;
    int cg = t & 7;                       // 16-col group
    float accA[16], accB[16];
#pragma unroll
    for (int j = 0; j < 16; ++j) { accA[j] = 0.f; accB[j] = 0.f; }
    const float* wp = &W1s[cg * 20];
#pragma unroll 4
    for (int k = 0; k < F_IN; ++k) {
        float a = xs[nA * 68 + k];
        float b = xs[nB * 68 + k];
        const float* wr = wp + k * 160;
#pragma unroll
        for (int j = 0; j < 4; ++j) {
            float4 w = *(const float4*)(wr + 4 * j);
            accA[4 * j + 0] += a * w.x;
            accA[4 * j + 1] += a * w.y;
            accA[4 * j + 2] += a * w.z;
            accA[4 * j + 3] += a * w.w;
            accB[4 * j + 0] += b * w.x;
            accB[4 * j + 1] += b * w.y;
            accB[4 * j + 2] += b * w.z;
            accB[4 * j + 3] += b * w.w;
        }
    }
    // ---- attention logits (both nodes) ----
    int head = cg >> 1, hoff = (cg & 1) * 16;
    const float* asp = a_src1 + head * 32 + hoff;
    const float* adp = a_dst1 + head * 32 + hoff;
    float psA = 0.f, pdA = 0.f, psB = 0.f, pdB = 0.f;
#pragma unroll
    for (int j = 0; j < 16; ++j) {
        psA += accA[j] * asp[j]; pdA += accA[j] * adp[j];
        psB += accB[j] * asp[j]; pdB += accB[j] * adp[j];
    }
    psA += __shfl_xor(psA, 1);
    pdA += __shfl_xor(pdA, 1);
    psB += __shfl_xor(psB, 1);
    pdB += __shfl_xor(pdB, 1);
    if ((cg & 1) == 0) {
        als1[(size_t)(n0 + nA) * 4 + head] = psA;
        ald1[(size_t)(n0 + nA) * 4 + head] = pdA;
        als1[(size_t)(n0 + nB) * 4 + head] = psB;
        ald1[(size_t)(n0 + nB) * 4 + head] = pdB;
    }
    // ---- pack 16 bf16 per node; store head-major: [head][N][16 uints] ----
    unsigned uA[8], uB[8];
#pragma unroll
    for (int j = 0; j < 8; ++j) {
        uA[j] = ((unsigned)f2bf(accA[2 * j + 1]) << 16) | (unsigned)f2bf(accA[2 * j]);
        uB[j] = ((unsigned)f2bf(accB[2 * j + 1]) << 16) | (unsigned)f2bf(accB[2 * j]);
    }
    unsigned* hu = (unsigned*)hth;
    size_t bA = (size_t)head * (N_NODES * 16) + (size_t)(n0 + nA) * 16 + (cg & 1) * 8;
    size_t bB = (size_t)head * (N_NODES * 16) + (size_t)(n0 + nB) * 16 + (cg & 1) * 8;
    ((uint4*)(hu + bA))[0] = make_uint4(uA[0], uA[1], uA[2], uA[3]);
    ((uint4*)(hu + bA))[1] = make_uint4(uA[4], uA[5], uA[6], uA[7]);
    ((uint4*)(hu + bB))[0] = make_uint4(uB[0], uB[1], uB[2], uB[3]);
    ((uint4*)(hu + bB))[1] = make_uint4(uB[4], uB[5], uB[6], uB[7]);
}

// ---- agg1_k: HEAD-PHASED layer-1 aggregation.
// grid = 4 * (N/16); h = blockIdx.x / (N/16). Per phase the gathered table is
// one head's 6.5 MB strip -> ~L2-resident (vs 26 MB before). Wave = 4 dst
// groups x 16 lanes; per 16-edge group each lane loads its own col/als1 and
// computes its exp ONCE, then (s,w) are shfl-broadcast for the FMA gathers.
// h1 channel layout (head-major) is unchanged -> dense2_k untouched.
__global__ __launch_bounds__(256, 8) void agg1_k(
    const int* __restrict__ row_ptr, const int* __restrict__ row_end,
    const unsigned* __restrict__ col, const unsigned* __restrict__ hthu,
    const float* __restrict__ als1, const float* __restrict__ ald1,
    const float* __restrict__ b1, float* __restrict__ h1)
{
    const int BLKS_PER_H = N_NODES / 16;
    int h  = blockIdx.x / BLKS_PER_H;
    int db = blockIdx.x - h * BLKS_PER_H;
    int t = threadIdx.x;
    int grp = t >> 4;            // dst slot in block (0..15)
    int sub = t & 15;            // channel-pair within head
    int lane = t & 63;
    int base = lane & 48;        // 16-lane group base within wave
    int d = db * 16 + grp;
    const unsigned* th = hthu + (size_t)h * (N_NODES * 16);

    float adv = ald1[d * 4 + h];
    float wself = __expf(lrelu(als1[d * 4 + h] + adv));
    unsigned pself = th[(size_t)d * 16 + sub];
    float a0 = wself * bfLO(pself);
    float a1 = wself * bfHI(pself);
    float wsum = 0.f;

    int e0 = row_ptr[d], e1 = row_end[d];
    for (int e = e0; __any(e < e1); e += 16) {
        int ei = e + sub;
        bool valid = ei < e1;
        unsigned svv = col[valid ? ei : e0];
        float av = als1[(size_t)svv * 4 + h];
        float w = valid ? __expf(lrelu(av + adv)) : 0.f;
        wsum += w;
#pragma unroll
        for (int i = 0; i < 16; ++i) {
            int   si = __shfl((int)svv, base + i);
            float wi = __shfl(w, base + i);
            unsigned pi = th[(size_t)si * 16 + sub];
            a0 += wi * bfLO(pi);
            a1 += wi * bfHI(pi);
        }
    }
    // den over the 16 lanes of this dst (xor masks stay in-group)
    wsum += __shfl_xor(wsum, 1);
    wsum += __shfl_xor(wsum, 2);
    wsum += __shfl_xor(wsum, 4);
    wsum += __shfl_xor(wsum, 8);
    float inv = 1.f / (wsum + wself);
    float2 bb = ((const float2*)b1)[h * 16 + sub];
    float2 o;
    o.x = elu(a0 * inv + bb.x);
    o.y = elu(a1 * inv + bb.y);
    ((float2*)h1)[(size_t)d * 64 + h * 16 + sub] = o;
}

// ---- dense2_k: h2 = h1 @ W2 (bf16 store) + layer-2 logits ----
// Register-blocked: 64 nodes/block, 2 nodes x 4 outs/thread, k unrolled x4.
__global__ __launch_bounds__(256) void dense2_k(
    const float* __restrict__ h1, const float* __restrict__ W2,
    const float* __restrict__ a_src2, const float* __restrict__ a_dst2,
    unsigned short* __restrict__ h2h, float* __restrict__ al_s2, float* __restrict__ al_d2)
{
    __shared__ float hs[64 * 132];    // stride 132: 16B-aligned, ==4 mod 32
    __shared__ float W2s[128 * 32];
    __shared__ float h2s[64 * 36];
    int t = threadIdx.x;
    int n0 = blockIdx.x * 64;
#pragma unroll
    for (int j = 0; j < 8; ++j) {
        int q = t + 256 * j;                 // 2048 float4 over 64x128
        int n = q >> 5, c0 = (q & 31) * 4;
        *(float4*)&hs[n * 132 + c0] = ((const float4*)h1)[(size_t)n0 * 32 + q];
    }
#pragma unroll
    for (int j = 0; j < 4; ++j) {
        int q = t + 256 * j;                 // 1024 float4 over 128x32
        ((float4*)W2s)[q] = ((const float4*)W2)[q];
    }
    __syncthreads();
    int ng = t >> 3, og = t & 7;
    int nA = 2 * ng, nB = nA + 1;
    int o4 = og * 4;
    float4 aA = make_float4(0.f, 0.f, 0.f, 0.f);
    float4 aB = aA;
#pragma unroll 8
    for (int k = 0; k < F_MID; k += 4) {
        float4 hA = *(const float4*)&hs[nA * 132 + k];
        float4 hB = *(const float4*)&hs[nB * 132 + k];
        float4 w0 = *(const float4*)&W2s[(k + 0) * 32 + o4];
        float4 w1 = *(const float4*)&W2s[(k + 1) * 32 + o4];
        float4 w2 = *(const float4*)&W2s[(k + 2) * 32 + o4];
        float4 w3 = *(const float4*)&W2s[(k + 3) * 32 + o4];
        aA.x += hA.x * w0.x; aA.y += hA.x * w0.y; aA.z += hA.x * w0.z; aA.w += hA.x * w0.w;
        aA.x += hA.y * w1.x; aA.y += hA.y * w1.y; aA.z += hA.y * w1.z; aA.w += hA.y * w1.w;
        aA.x += hA.z * w2.x; aA.y += hA.z * w2.y; aA.z += hA.z * w2.z; aA.w += hA.z * w2.w;
        aA.x += hA.w * w3.x; aA.y += hA.w * w3.y; aA.z += hA.w * w3.z; aA.w += hA.w * w3.w;
        aB.x += hB.x * w0.x; aB.y += hB.x * w0.y; aB.z += hB.x * w0.z; aB.w += hB.x * w0.w;
        aB.x += hB.y * w1.x; aB.y += hB.y * w1.y; aB.z += hB.y * w1.z; aB.w += hB.y * w1.w;
        aB.x += hB.z * w2.x; aB.y += hB.z * w2.y; aB.z += hB.z * w2.z; aB.w += hB.z * w2.w;
        aB.x += hB.w * w3.x; aB.y += hB.w * w3.y; aB.z += hB.w * w3.z; aB.w += hB.w * w3.w;
    }
    unsigned loA = ((unsigned)f2bf(aA.y) << 16) | (unsigned)f2bf(aA.x);
    unsigned hiA = ((unsigned)f2bf(aA.w) << 16) | (unsigned)f2bf(aA.z);
    ((uint2*)h2h)[(((size_t)(n0 + nA)) * C2 + o4) >> 2] = make_uint2(loA, hiA);
    unsigned loB = ((unsigned)f2bf(aB.y) << 16) | (unsigned)f2bf(aB.x);
    unsigned hiB = ((unsigned)f2bf(aB.w) << 16) | (unsigned)f2bf(aB.z);
    ((uint2*)h2h)[(((size_t)(n0 + nB)) * C2 + o4) >> 2] = make_uint2(loB, hiB);
    *(float4*)&h2s[nA * 36 + o4] = aA;
    *(float4*)&h2s[nB * 36 + o4] = aB;
    __syncthreads();
    if (t < 128) {
        int which = t >> 6, nn = t & 63;
        const float* a = which ? a_dst2 : a_src2;
        float s = 0.f;
#pragma unroll
        for (int k = 0; k < C2; ++k) s += h2s[nn * 36 + k] * a[k];
        if (which) al_d2[n0 + nn] = s;
        else       al_s2[n0 + nn] = s;
    }
}

// ---- gather2: 8 lanes/dst, 32 dsts/block, edge-layout shfl form.
// FUSED classifier head: last block (done-ticket) computes out[] directly.
__global__ __launch_bounds__(256, 8) void gather2(
    const int* __restrict__ row_ptr, const int* __restrict__ row_end,
    const unsigned* __restrict__ col, const float* __restrict__ al_src,
    const float* __restrict__ al_dst, const unsigned short* __restrict__ h2h,
    const float* __restrict__ b2, const int* __restrict__ batch,
    float* __restrict__ pooled, int* __restrict__ ticket,
    const float* __restrict__ clinical,
    const float* __restrict__ Wc1, const float* __restrict__ bc1,
    const float* __restrict__ Wc2, const float* __restrict__ bc2,
    float* __restrict__ out)
{
    __shared__ float sv[32][C2];
    __shared__ int lastFlag;
    int t = threadIdx.x;
    int r = t >> 3;               // dst slot in block (0..31)
    int sub = t & 7;              // channel-pair AND edge-slot
    int lane = t & 63;
    int base = lane & 56;         // 8-lane group base (wave-relative)
    int d = blockIdx.x * 32 + r;
    const uint2* h2v = (const uint2*)h2h;

    float ad = al_dst[d];
    float wself = __expf(lrelu(al_src[d] + ad));
    float4 v = bf2f4(h2v[(size_t)d * 8 + sub]);
    float ax = wself * v.x, ay = wself * v.y, az = wself * v.z, aw = wself * v.w;
    float wsum = 0.f;             // per-lane partial of den (edge-slot role)
    int e0 = row_ptr[d], e1 = row_end[d];

    for (int e = e0; __any(e < e1); e += 8) {
        int ei = e + sub;
        bool valid = ei < e1;
        unsigned svv = col[valid ? ei : 0];        // clamp to a safe address
        float av = al_src[(int)svv];
        float w = valid ? __expf(lrelu(av + ad)) : 0.f;
        wsum += w;
#pragma unroll
        for (int i = 0; i < 8; ++i) {
            int   si = __shfl((int)svv, base + i);
            float wi = __shfl(w, base + i);
            float4 xi = bf2f4(h2v[(size_t)si * 8 + sub]);
            ax += wi * xi.x; ay += wi * xi.y; az += wi * xi.z; aw += wi * xi.w;
        }
    }
    // reduce den over the 8 lanes of this dst (xor masks stay in-group)
    wsum += __shfl_xor(wsum, 1);
    wsum += __shfl_xor(wsum, 2);
    wsum += __shfl_xor(wsum, 4);
    float den = wsum + wself;

    float inv = 1.f / den;
    const float4 bv = ((const float4*)b2)[sub];
    sv[r][4 * sub + 0] = elu(ax * inv + bv.x);
    sv[r][4 * sub + 1] = elu(ay * inv + bv.y);
    sv[r][4 * sub + 2] = elu(az * inv + bv.z);
    sv[r][4 * sub + 3] = elu(aw * inv + bv.w);
    __syncthreads();
    int d0 = blockIdx.x * 32;
    int g0 = batch[d0], g1 = batch[d0 + 31];
    if (t < 64) {
        int which = t >> 5, ch = t & 31;
        int g = which ? g1 : g0;
        if (which == 0 || g1 != g0) {
            float s = 0.f;
            for (int rr = 0; rr < 32; ++rr)
                if (batch[d0 + rr] == g) s += sv[rr][ch];
            atomicAdd(&pooled[g * C2 + ch], s);
        }
    }
    // ---------- fused head: last block to finish computes out[] ----------
    __threadfence();
    __syncthreads();
    if (t == 0) lastFlag = (atomicAdd(ticket, 1) == (int)gridDim.x - 1);
    __syncthreads();
    if (lastFlag) {
        __threadfence();
        int g = t;                       // 256 threads = 256 graphs
        float fused[C2 + CLIN];
        const float invn = 1.f / 400.f;
#pragma unroll
        for (int c = 0; c < C2; ++c) fused[c] = pooled[g * C2 + c] * invn;
#pragma unroll
        for (int c = 0; c < CLIN; ++c) fused[C2 + c] = clinical[g * CLIN + c];
        float o = bc2[0];
#pragma unroll
        for (int j = 0; j < 16; ++j) {
            float acc = bc1[j];
#pragma unroll
            for (int k = 0; k < C2 + CLIN; ++k) acc += fused[k] * Wc1[k * 16 + j];
            o += (acc > 0.f ? acc : expm1f(acc)) * Wc2[j];
        }
        out[g] = o;
    }
}

extern "C" void kernel_launch(void* const* d_in, const int* in_sizes, int n_in,
                              void* d_out, int out_size, void* d_ws, size_t ws_size,
                              hipStream_t stream) {
    const float* x        = (const float*)d_in[0];
    const int*   ei       = (const int*)  d_in[1];
    const int*   batch    = (const int*)  d_in[2];
    const float* clinical = (const float*)d_in[3];
    const float* W1       = (const float*)d_in[4];
    const float* a_src1   = (const float*)d_in[5];
    const float* a_dst1   = (const float*)d_in[6];
    const float* b1       = (const float*)d_in[7];
    const float* W2       = (const float*)d_in[8];
    const float* a_src2   = (const float*)d_in[9];
    const float* a_dst2   = (const float*)d_in[10];
    const float* b2       = (const float*)d_in[11];
    const float* Wc1      = (const float*)d_in[12];
    const float* bc1      = (const float*)d_in[13];
    const float* Wc2      = (const float*)d_in[14];
    const float* bc2      = (const float*)d_in[15];
    float* out = (float*)d_out;

    const size_t N = N_NODES;
    float* ws = (float*)d_ws;
    size_t off = 0;
    float* als1   = ws + off; off += N * 4;
    float* ald1   = ws + off; off += N * 4;
    float* al_s2  = ws + off; off += N;
    float* al_d2  = ws + off; off += N;
    float* pooled = ws + off; off += (size_t)G_GRAPHS * C2;
    unsigned short* hth = (unsigned short*)(ws + off); off += N * F_MID / 2;  // bf16 h~ [4][N][32]
    float* h1     = ws + off; off += N * F_MID;                               // fp32 h1
    unsigned short* h2h = (unsigned short*)(ws + off); off += N * C2 / 2;     // bf16 h2
    int* row_ptr = (int*)(ws + off); off += N;
    int* row_end = (int*)(ws + off); off += N;
    int* gcnt    = (int*)(ws + off); off += 512;      // [0:256)=gcnt, [256]=ticket
    unsigned* binned = (unsigned*)(ws + off); off += (size_t)G_GRAPHS * CAPB; // also final col
    int* ticket = gcnt + 256;

    hipMemsetAsync(gcnt, 0, 512 * sizeof(int), stream);

    // CSR build: LDS binning
    bin_k  <<<N_EDGES / 4096, 256, 0, stream>>>(ei, gcnt, binned);
    build_k<<<G_GRAPHS, 512, 0, stream>>>(gcnt, binned, row_ptr, row_end);

    // h~ = x@W1 (bf16 head-major table) + layer-1 logits + pooled zeroing
    ht_k<<<N_NODES / 64, 256, 0, stream>>>(x, W1, a_src1, a_dst1, hth, als1, ald1, pooled);

    // head-phased layer-1 aggregation -> h1 fp32 (one head's 6.5MB strip hot at a time)
    agg1_k<<<4 * (N_NODES / 16), 256, 0, stream>>>(row_ptr, row_end, binned,
                                                   (const unsigned*)hth, als1, ald1,
                                                   b1, h1);

    // h2 = h1@W2 (bf16) + layer-2 logits
    dense2_k<<<N_NODES / 64, 256, 0, stream>>>(h1, W2, a_src2, a_dst2, h2h, al_s2, al_d2);

    // layer 2 gather (+ fused pooling + fused classifier head via done-ticket)
    gather2<<<N_NODES / 32, 256, 0, stream>>>(row_ptr, row_end, binned, al_s2, al_d2, h2h,
                                              b2, batch, pooled, ticket,
                                              clinical, Wc1, bc1, Wc2, bc2, out);
}

// Round 11
// 303.046 us; speedup vs baseline: 2.1676x; 2.1676x over previous
//
#include <hip/hip_runtime.h>
#include <math.h>

#define N_NODES 102400
#define N_EDGES 1638400
#define G_GRAPHS 256
#define NODES_PER_G 400
#define CAPB 7168          // per-graph edge bucket capacity (mean 6400, +9.6 sigma)
#define F_IN  64
#define H1    4
#define C1    32
#define F_MID 128
#define C2    32
#define CLIN  5
#define NEG   0.2f

__device__ __forceinline__ float lrelu(float x) { return x > 0.f ? x : NEG * x; }
__device__ __forceinline__ float elu(float x)   { return x > 0.f ? x : expm1f(x); }

// round-to-nearest-even fp32 -> bf16 (as ushort)
__device__ __forceinline__ unsigned short f2bf(float f) {
    unsigned u = __float_as_uint(f);
    u = (u + 0x7fffu + ((u >> 16) & 1u)) >> 16;
    return (unsigned short)u;
}
__device__ __forceinline__ float bfLO(unsigned p) { return __uint_as_float(p << 16); }
__device__ __forceinline__ float bfHI(unsigned p) { return __uint_as_float(p & 0xffff0000u); }
// unpack 4 bf16 (uint2) -> float4
__device__ __forceinline__ float4 bf2f4(uint2 p) {
    return make_float4(__uint_as_float(p.x << 16), __uint_as_float(p.x & 0xffff0000u),
                       __uint_as_float(p.y << 16), __uint_as_float(p.y & 0xffff0000u));
}

// ---------------- CSR build, LDS-binned (no global random atomics) ----------------
__global__ __launch_bounds__(256) void bin_k(const int* __restrict__ ei,
                                             int* __restrict__ gcnt,
                                             unsigned* __restrict__ binned) {
    __shared__ int hist[256];
    __shared__ int off[256];
    int t = threadIdx.x;
    hist[t] = 0;
    __syncthreads();
    int i0 = blockIdx.x * 4096;
#pragma unroll
    for (int j = 0; j < 16; ++j) {
        int d = ei[N_EDGES + i0 + j * 256 + t];
        atomicAdd(&hist[d / NODES_PER_G], 1);
    }
    __syncthreads();
    off[t] = atomicAdd(&gcnt[t], hist[t]);
    hist[t] = 0;                         // reuse as per-bucket running slot
    __syncthreads();
#pragma unroll
    for (int j = 0; j < 16; ++j) {
        int idx = i0 + j * 256 + t;
        int s = ei[idx];
        int d = ei[N_EDGES + idx];
        int g = d / NODES_PER_G;
        int dl = d - g * NODES_PER_G;
        int slot = atomicAdd(&hist[g], 1);
        binned[(size_t)g * CAPB + off[g] + slot] = (unsigned)s | ((unsigned)dl << 17);
    }
}

__global__ __launch_bounds__(512) void build_k(
    const int* __restrict__ gcnt, unsigned* __restrict__ binned,
    int* __restrict__ row_ptr, int* __restrict__ row_end)
{
    __shared__ unsigned edg[CAPB];
    __shared__ int coll[CAPB];
    __shared__ int hist[512];
    __shared__ int cur[NODES_PER_G];
    int g = blockIdx.x, t = threadIdx.x;
    int ne = gcnt[g];
    size_t base = (size_t)g * CAPB;
    for (int i = t; i < ne; i += 512) edg[i] = binned[base + i];
    hist[t] = 0;
    __syncthreads();
    for (int i = t; i < ne; i += 512) atomicAdd(&hist[edg[i] >> 17], 1);
    __syncthreads();
    int v = hist[t];
    for (int off = 1; off < 512; off <<= 1) {
        int tmp = (t >= off) ? hist[t - off] : 0;
        __syncthreads();
        hist[t] += tmp;
        __syncthreads();
    }
    int excl = hist[t] - v;
    if (t < NODES_PER_G) {
        cur[t] = excl;
        row_ptr[g * NODES_PER_G + t] = (int)base + excl;
    }
    __syncthreads();
    for (int i = t; i < ne; i += 512) {
        unsigned e = edg[i];
        int pos = atomicAdd(&cur[e >> 17], 1);
        coll[pos] = (int)(e & 0x1FFFFu);
    }
    __syncthreads();
    if (t < NODES_PER_G) row_end[g * NODES_PER_G + t] = (int)base + cur[t];
    for (int i = t; i < ne; i += 512) binned[base + i] = (unsigned)coll[i];
}

// ---- ht_k: h~ = x @ W1 (fp32 accum) -> bf16 table hth [N][128]
//            + layer-1 logits split: als1 (src), ald1 (dst)
// Register-blocked: 64 nodes/block, 2 nodes/thread x 16 outs.
__global__ __launch_bounds__(256) void ht_k(
    const float* __restrict__ x, const float* __restrict__ W1,
    const float* __restrict__ a_src1, const float* __restrict__ a_dst1,
    unsigned short* __restrict__ hth, float* __restrict__ als1, float* __restrict__ ald1,
    float* __restrict__ pooled)
{
    __shared__ float xs[64 * 68];      // stride 68: 16B-aligned, ==4 mod 32
    __shared__ float W1s[64 * 160];    // skewed: k*160 + (c0>>4)*20 + (c0&15)
    int t = threadIdx.x;
    int n0 = blockIdx.x * 64;
    if (blockIdx.x == 0) {
        for (int j = t; j < G_GRAPHS * C2; j += 256) pooled[j] = 0.f;
    }
#pragma unroll
    for (int j = 0; j < 4; ++j) {
        int q = t + 256 * j;              // 1024 float4 over 64x64
        int n = q >> 4, c0 = (q & 15) * 4;
        *(float4*)&xs[n * 68 + c0] = ((const float4*)x)[(size_t)n0 * 16 + q];
    }
#pragma unroll
    for (int j = 0; j < 8; ++j) {
        int q = t + 256 * j;              // 2048 float4 over 64x128
        int k = q >> 5, c0 = (q & 31) * 4;
        float4 v = ((const float4*)W1)[q];
        *(float4*)&W1s[k * 160 + (c0 >> 4) * 20 + (c0 & 15)] = v;
    }
    __syncthreads();
    int np = t >> 3;                      // node pair 0..31
    int nA = 2 * np, nB = nA + 1;
    int cg = t & 7;                       // 16-col group
    float accA[16], accB[16];
#pragma unroll
    for (int j = 0; j < 16; ++j) { accA[j] = 0.f; accB[j] = 0.f; }
    const float* wp = &W1s[cg * 20];
#pragma unroll 4
    for (int k = 0; k < F_IN; ++k) {
        float a = xs[nA * 68 + k];
        float b = xs[nB * 68 + k];
        const float* wr = wp + k * 160;
#pragma unroll
        for (int j = 0; j < 4; ++j) {
            float4 w = *(const float4*)(wr + 4 * j);
            accA[4 * j + 0] += a * w.x;
            accA[4 * j + 1] += a * w.y;
            accA[4 * j + 2] += a * w.z;
            accA[4 * j + 3] += a * w.w;
            accB[4 * j + 0] += b * w.x;
            accB[4 * j + 1] += b * w.y;
            accB[4 * j + 2] += b * w.z;
            accB[4 * j + 3] += b * w.w;
        }
    }
    // ---- attention logits (both nodes) ----
    int head = cg >> 1, hoff = (cg & 1) * 16;
    const float* asp = a_src1 + head * 32 + hoff;
    const float* adp = a_dst1 + head * 32 + hoff;
    float psA = 0.f, pdA = 0.f, psB = 0.f, pdB = 0.f;
#pragma unroll
    for (int j = 0; j < 16; ++j) {
        psA += accA[j] * asp[j]; pdA += accA[j] * adp[j];
        psB += accB[j] * asp[j]; pdB += accB[j] * adp[j];
    }
    psA += __shfl_xor(psA, 1);
    pdA += __shfl_xor(pdA, 1);
    psB += __shfl_xor(psB, 1);
    pdB += __shfl_xor(pdB, 1);
    if ((cg & 1) == 0) {
        als1[(size_t)(n0 + nA) * 4 + head] = psA;
        ald1[(size_t)(n0 + nA) * 4 + head] = pdA;
        als1[(size_t)(n0 + nB) * 4 + head] = psB;
        ald1[(size_t)(n0 + nB) * 4 + head] = pdB;
    }
    // ---- pack 16 bf16 per node and store ----
    unsigned uA[8], uB[8];
#pragma unroll
    for (int j = 0; j < 8; ++j) {
        uA[j] = ((unsigned)f2bf(accA[2 * j + 1]) << 16) | (unsigned)f2bf(accA[2 * j]);
        uB[j] = ((unsigned)f2bf(accB[2 * j + 1]) << 16) | (unsigned)f2bf(accB[2 * j]);
    }
    uint4* hpA = (uint4*)(hth + ((size_t)(n0 + nA) * F_MID + cg * 16));
    hpA[0] = make_uint4(uA[0], uA[1], uA[2], uA[3]);
    hpA[1] = make_uint4(uA[4], uA[5], uA[6], uA[7]);
    uint4* hpB = (uint4*)(hth + ((size_t)(n0 + nB) * F_MID + cg * 16));
    hpB[0] = make_uint4(uB[0], uB[1], uB[2], uB[3]);
    hpB[1] = make_uint4(uB[4], uB[5], uB[6], uB[7]);
}

// ---- agg1_k: barrier-free, zero-LDS layer-1 aggregation (one wave per dst).
// r6-proven form: weight-layout lanes (lane = edge + 8*head) compute each exp
// chain once, shfl-broadcast to channel lanes. Masked 8-wide tail.
__global__ __launch_bounds__(256, 8) void agg1_k(
    const int* __restrict__ row_ptr, const int* __restrict__ row_end,
    const unsigned* __restrict__ col, const unsigned short* __restrict__ hth,
    const float* __restrict__ als1, const float* __restrict__ ald1,
    const float* __restrict__ b1, float* __restrict__ h1)
{
    int t = threadIdx.x;
    int wv = t >> 6, lane = t & 63, h = lane >> 4;
    int hw = (lane >> 3) & 3;          // weight-layout head (dup in upper half)
    int ew = lane & 7;                 // weight-layout edge slot
    int d = blockIdx.x * 4 + wv;
    const unsigned* hv = (const unsigned*)hth;    // [N][64] packed bf16 pairs

    float adv  = ald1[d * 4 + h];      // channel-layout (self loop)
    float advB = ald1[d * 4 + hw];     // weight-layout (edge loop)
    float w = __expf(lrelu(als1[d * 4 + h] + adv));     // self loop
    unsigned p = hv[(size_t)d * 64 + lane];
    float a0 = w * bfLO(p), a1 = w * bfHI(p);
    float den = w;

    int bidx = (h << 3);               // base shfl index for this channel-lane's head

    int e0 = __builtin_amdgcn_readfirstlane(row_ptr[d]);
    int e1 = __builtin_amdgcn_readfirstlane(row_end[d]);
    int e = e0;
    for (; e + 8 <= e1; e += 8) {
        unsigned sv = col[e + ew];                 // 1 coalesced 32B load
        int s0 = __builtin_amdgcn_readlane(sv, 0);
        int s1 = __builtin_amdgcn_readlane(sv, 1);
        int s2 = __builtin_amdgcn_readlane(sv, 2);
        int s3 = __builtin_amdgcn_readlane(sv, 3);
        int s4 = __builtin_amdgcn_readlane(sv, 4);
        int s5 = __builtin_amdgcn_readlane(sv, 5);
        int s6 = __builtin_amdgcn_readlane(sv, 6);
        int s7 = __builtin_amdgcn_readlane(sv, 7);
        unsigned p0 = hv[(size_t)s0 * 64 + lane];
        unsigned p1 = hv[(size_t)s1 * 64 + lane];
        unsigned p2 = hv[(size_t)s2 * 64 + lane];
        unsigned p3 = hv[(size_t)s3 * 64 + lane];
        unsigned p4 = hv[(size_t)s4 * 64 + lane];
        unsigned p5 = hv[(size_t)s5 * 64 + lane];
        unsigned p6 = hv[(size_t)s6 * 64 + lane];
        unsigned p7 = hv[(size_t)s7 * 64 + lane];
        float avv  = als1[(size_t)sv * 4 + hw];    // 1 gather (weight layout)
        float wAll = __expf(lrelu(avv + advB));    // 1 exp chain
        float w0 = __shfl(wAll, bidx + 0);
        float w1 = __shfl(wAll, bidx + 1);
        float w2 = __shfl(wAll, bidx + 2);
        float w3 = __shfl(wAll, bidx + 3);
        float w4 = __shfl(wAll, bidx + 4);
        float w5 = __shfl(wAll, bidx + 5);
        float w6 = __shfl(wAll, bidx + 6);
        float w7 = __shfl(wAll, bidx + 7);
        a0 += w0 * bfLO(p0) + w1 * bfLO(p1) + w2 * bfLO(p2) + w3 * bfLO(p3);
        a0 += w4 * bfLO(p4) + w5 * bfLO(p5) + w6 * bfLO(p6) + w7 * bfLO(p7);
        a1 += w0 * bfHI(p0) + w1 * bfHI(p1) + w2 * bfHI(p2) + w3 * bfHI(p3);
        a1 += w4 * bfHI(p4) + w5 * bfHI(p5) + w6 * bfHI(p6) + w7 * bfHI(p7);
        den += w0 + w1 + w2 + w3 + w4 + w5 + w6 + w7;
    }
    if (e < e1) {   // masked 8-wide tail: one latency round instead of up to 7
        int iv = e + ew;
        bool inr = iv < e1;
        unsigned sv = col[inr ? iv : (e1 - 1)];
        int s0 = __builtin_amdgcn_readlane(sv, 0);
        int s1 = __builtin_amdgcn_readlane(sv, 1);
        int s2 = __builtin_amdgcn_readlane(sv, 2);
        int s3 = __builtin_amdgcn_readlane(sv, 3);
        int s4 = __builtin_amdgcn_readlane(sv, 4);
        int s5 = __builtin_amdgcn_readlane(sv, 5);
        int s6 = __builtin_amdgcn_readlane(sv, 6);
        int s7 = __builtin_amdgcn_readlane(sv, 7);
        unsigned p0 = hv[(size_t)s0 * 64 + lane];
        unsigned p1 = hv[(size_t)s1 * 64 + lane];
        unsigned p2 = hv[(size_t)s2 * 64 + lane];
        unsigned p3 = hv[(size_t)s3 * 64 + lane];
        unsigned p4 = hv[(size_t)s4 * 64 + lane];
        unsigned p5 = hv[(size_t)s5 * 64 + lane];
        unsigned p6 = hv[(size_t)s6 * 64 + lane];
        unsigned p7 = hv[(size_t)s7 * 64 + lane];
        float avv  = als1[(size_t)sv * 4 + hw];
        float wAll = inr ? __expf(lrelu(avv + advB)) : 0.f;
        float w0 = __shfl(wAll, bidx + 0);
        float w1 = __shfl(wAll, bidx + 1);
        float w2 = __shfl(wAll, bidx + 2);
        float w3 = __shfl(wAll, bidx + 3);
        float w4 = __shfl(wAll, bidx + 4);
        float w5 = __shfl(wAll, bidx + 5);
        float w6 = __shfl(wAll, bidx + 6);
        float w7 = __shfl(wAll, bidx + 7);
        a0 += w0 * bfLO(p0) + w1 * bfLO(p1) + w2 * bfLO(p2) + w3 * bfLO(p3);
        a0 += w4 * bfLO(p4) + w5 * bfLO(p5) + w6 * bfLO(p6) + w7 * bfLO(p7);
        a1 += w0 * bfHI(p0) + w1 * bfHI(p1) + w2 * bfHI(p2) + w3 * bfHI(p3);
        a1 += w4 * bfHI(p4) + w5 * bfHI(p5) + w6 * bfHI(p6) + w7 * bfHI(p7);
        den += w0 + w1 + w2 + w3 + w4 + w5 + w6 + w7;
    }
    float inv = 1.f / den;
    float2 bb = ((const float2*)b1)[lane];
    float2 o;
    o.x = elu(a0 * inv + bb.x);
    o.y = elu(a1 * inv + bb.y);
    ((float2*)h1)[(size_t)d * 64 + lane] = o;
}

// ---- dense2_k: h2 = h1 @ W2 (bf16 store) + layer-2 logits ----
// Register-blocked: 64 nodes/block, 2 nodes x 4 outs/thread, k unrolled x4
// with b128 hs reads -> 6 b128 per 32 FMAs.
__global__ __launch_bounds__(256) void dense2_k(
    const float* __restrict__ h1, const float* __restrict__ W2,
    const float* __restrict__ a_src2, const float* __restrict__ a_dst2,
    unsigned short* __restrict__ h2h, float* __restrict__ al_s2, float* __restrict__ al_d2)
{
    __shared__ float hs[64 * 132];    // stride 132: 16B-aligned, ==4 mod 32
    __shared__ float W2s[128 * 32];
    __shared__ float h2s[64 * 36];
    int t = threadIdx.x;
    int n0 = blockIdx.x * 64;
#pragma unroll
    for (int j = 0; j < 8; ++j) {
        int q = t + 256 * j;                 // 2048 float4 over 64x128
        int n = q >> 5, c0 = (q & 31) * 4;
        *(float4*)&hs[n * 132 + c0] = ((const float4*)h1)[(size_t)n0 * 32 + q];
    }
#pragma unroll
    for (int j = 0; j < 4; ++j) {
        int q = t + 256 * j;                 // 1024 float4 over 128x32
        ((float4*)W2s)[q] = ((const float4*)W2)[q];
    }
    __syncthreads();
    int ng = t >> 3, og = t & 7;
    int nA = 2 * ng, nB = nA + 1;
    int o4 = og * 4;
    float4 aA = make_float4(0.f, 0.f, 0.f, 0.f);
    float4 aB = aA;
#pragma unroll 8
    for (int k = 0; k < F_MID; k += 4) {
        float4 hA = *(const float4*)&hs[nA * 132 + k];
        float4 hB = *(const float4*)&hs[nB * 132 + k];
        float4 w0 = *(const float4*)&W2s[(k + 0) * 32 + o4];
        float4 w1 = *(const float4*)&W2s[(k + 1) * 32 + o4];
        float4 w2 = *(const float4*)&W2s[(k + 2) * 32 + o4];
        float4 w3 = *(const float4*)&W2s[(k + 3) * 32 + o4];
        aA.x += hA.x * w0.x; aA.y += hA.x * w0.y; aA.z += hA.x * w0.z; aA.w += hA.x * w0.w;
        aA.x += hA.y * w1.x; aA.y += hA.y * w1.y; aA.z += hA.y * w1.z; aA.w += hA.y * w1.w;
        aA.x += hA.z * w2.x; aA.y += hA.z * w2.y; aA.z += hA.z * w2.z; aA.w += hA.z * w2.w;
        aA.x += hA.w * w3.x; aA.y += hA.w * w3.y; aA.z += hA.w * w3.z; aA.w += hA.w * w3.w;
        aB.x += hB.x * w0.x; aB.y += hB.x * w0.y; aB.z += hB.x * w0.z; aB.w += hB.x * w0.w;
        aB.x += hB.y * w1.x; aB.y += hB.y * w1.y; aB.z += hB.y * w1.z; aB.w += hB.y * w1.w;
        aB.x += hB.z * w2.x; aB.y += hB.z * w2.y; aB.z += hB.z * w2.z; aB.w += hB.z * w2.w;
        aB.x += hB.w * w3.x; aB.y += hB.w * w3.y; aB.z += hB.w * w3.z; aB.w += hB.w * w3.w;
    }
    unsigned loA = ((unsigned)f2bf(aA.y) << 16) | (unsigned)f2bf(aA.x);
    unsigned hiA = ((unsigned)f2bf(aA.w) << 16) | (unsigned)f2bf(aA.z);
    ((uint2*)h2h)[(((size_t)(n0 + nA)) * C2 + o4) >> 2] = make_uint2(loA, hiA);
    unsigned loB = ((unsigned)f2bf(aB.y) << 16) | (unsigned)f2bf(aB.x);
    unsigned hiB = ((unsigned)f2bf(aB.w) << 16) | (unsigned)f2bf(aB.z);
    ((uint2*)h2h)[(((size_t)(n0 + nB)) * C2 + o4) >> 2] = make_uint2(loB, hiB);
    *(float4*)&h2s[nA * 36 + o4] = aA;
    *(float4*)&h2s[nB * 36 + o4] = aB;
    __syncthreads();
    if (t < 128) {
        int which = t >> 6, nn = t & 63;
        const float* a = which ? a_dst2 : a_src2;
        float s = 0.f;
#pragma unroll
        for (int k = 0; k < C2; ++k) s += h2s[nn * 36 + k] * a[k];
        if (which) al_d2[n0 + nn] = s;
        else       al_s2[n0 + nn] = s;
    }
}

// ---- gather2: 8 lanes/dst, 32 dsts/block. Edge-layout lane duality:
// lane (dst, sub) loads col[e+sub] + al_src ONCE per 8-edge group, computes
// its exp once, then s_i/w_i shfl-broadcast to the channel role of the same
// lanes for the FMA block.
__global__ __launch_bounds__(256, 8) void gather2(
    const int* __restrict__ row_ptr, const int* __restrict__ row_end,
    const unsigned* __restrict__ col, const float* __restrict__ al_src,
    const float* __restrict__ al_dst, const unsigned short* __restrict__ h2h,
    const float* __restrict__ b2, const int* __restrict__ batch,
    float* __restrict__ pooled)
{
    __shared__ float sv[32][C2];
    int t = threadIdx.x;
    int r = t >> 3;               // dst slot in block (0..31)
    int sub = t & 7;              // channel-pair AND edge-slot
    int lane = t & 63;
    int base = lane & 56;         // 8-lane group base (wave-relative)
    int d = blockIdx.x * 32 + r;
    const uint2* h2v = (const uint2*)h2h;

    float ad = al_dst[d];
    float wself = __expf(lrelu(al_src[d] + ad));
    float4 v = bf2f4(h2v[(size_t)d * 8 + sub]);
    float ax = wself * v.x, ay = wself * v.y, az = wself * v.z, aw = wself * v.w;
    float wsum = 0.f;             // per-lane partial of den (edge-slot role)
    int e0 = row_ptr[d], e1 = row_end[d];

    for (int e = e0; __any(e < e1); e += 8) {
        int ei = e + sub;
        bool valid = ei < e1;
        unsigned svv = col[valid ? ei : 0];        // clamp to a safe address
        float av = al_src[(int)svv];
        float w = valid ? __expf(lrelu(av + ad)) : 0.f;
        wsum += w;
#pragma unroll
        for (int i = 0; i < 8; ++i) {
            int   si = __shfl((int)svv, base + i);
            float wi = __shfl(w, base + i);
            float4 xi = bf2f4(h2v[(size_t)si * 8 + sub]);
            ax += wi * xi.x; ay += wi * xi.y; az += wi * xi.z; aw += wi * xi.w;
        }
    }
    // reduce den over the 8 lanes of this dst (xor masks stay in-group)
    wsum += __shfl_xor(wsum, 1);
    wsum += __shfl_xor(wsum, 2);
    wsum += __shfl_xor(wsum, 4);
    float den = wsum + wself;

    float inv = 1.f / den;
    const float4 bv = ((const float4*)b2)[sub];
    sv[r][4 * sub + 0] = elu(ax * inv + bv.x);
    sv[r][4 * sub + 1] = elu(ay * inv + bv.y);
    sv[r][4 * sub + 2] = elu(az * inv + bv.z);
    sv[r][4 * sub + 3] = elu(aw * inv + bv.w);
    __syncthreads();
    int d0 = blockIdx.x * 32;
    int g0 = batch[d0], g1 = batch[d0 + 31];
    if (t < 64) {
        int which = t >> 5, ch = t & 31;
        int g = which ? g1 : g0;
        if (which == 0 || g1 != g0) {
            float s = 0.f;
            for (int rr = 0; rr < 32; ++rr)
                if (batch[d0 + rr] == g) s += sv[rr][ch];
            atomicAdd(&pooled[g * C2 + ch], s);
        }
    }
}

// ---- classifier head: one thread per graph (400 nodes/graph exactly) ----
__global__ __launch_bounds__(256) void head_k(
    const float* __restrict__ pooled, const float* __restrict__ clinical,
    const float* __restrict__ Wc1, const float* __restrict__ bc1,
    const float* __restrict__ Wc2, const float* __restrict__ bc2,
    float* __restrict__ out)
{
    int g = threadIdx.x;
    float fused[C2 + CLIN];
    const float inv = 1.f / 400.f;
#pragma unroll
    for (int c = 0; c < C2; ++c) fused[c] = pooled[g * C2 + c] * inv;
#pragma unroll
    for (int c = 0; c < CLIN; ++c) fused[C2 + c] = clinical[g * CLIN + c];
    float o = bc2[0];
#pragma unroll
    for (int j = 0; j < 16; ++j) {
        float acc = bc1[j];
#pragma unroll
        for (int k = 0; k < C2 + CLIN; ++k) acc += fused[k] * Wc1[k * 16 + j];
        o += (acc > 0.f ? acc : expm1f(acc)) * Wc2[j];
    }
    out[g] = o;
}

extern "C" void kernel_launch(void* const* d_in, const int* in_sizes, int n_in,
                              void* d_out, int out_size, void* d_ws, size_t ws_size,
                              hipStream_t stream) {
    const float* x        = (const float*)d_in[0];
    const int*   ei       = (const int*)  d_in[1];
    const int*   batch    = (const int*)  d_in[2];
    const float* clinical = (const float*)d_in[3];
    const float* W1       = (const float*)d_in[4];
    const float* a_src1   = (const float*)d_in[5];
    const float* a_dst1   = (const float*)d_in[6];
    const float* b1       = (const float*)d_in[7];
    const float* W2       = (const float*)d_in[8];
    const float* a_src2   = (const float*)d_in[9];
    const float* a_dst2   = (const float*)d_in[10];
    const float* b2       = (const float*)d_in[11];
    const float* Wc1      = (const float*)d_in[12];
    const float* bc1      = (const float*)d_in[13];
    const float* Wc2      = (const float*)d_in[14];
    const float* bc2      = (const float*)d_in[15];
    float* out = (float*)d_out;

    const size_t N = N_NODES;
    float* ws = (float*)d_ws;
    size_t off = 0;
    float* als1   = ws + off; off += N * 4;
    float* ald1   = ws + off; off += N * 4;
    float* al_s2  = ws + off; off += N;
    float* al_d2  = ws + off; off += N;
    float* pooled = ws + off; off += (size_t)G_GRAPHS * C2;
    unsigned short* hth = (unsigned short*)(ws + off); off += N * F_MID / 2;  // bf16 h~
    float* h1     = ws + off; off += N * F_MID;                               // fp32 h1
    unsigned short* h2h = (unsigned short*)(ws + off); off += N * C2 / 2;     // bf16 h2
    int* row_ptr = (int*)(ws + off); off += N;
    int* row_end = (int*)(ws + off); off += N;
    int* gcnt    = (int*)(ws + off); off += 256;
    unsigned* binned = (unsigned*)(ws + off); off += (size_t)G_GRAPHS * CAPB; // also final col

    hipMemsetAsync(gcnt, 0, 256 * sizeof(int), stream);

    // CSR build: LDS binning
    bin_k  <<<N_EDGES / 4096, 256, 0, stream>>>(ei, gcnt, binned);
    build_k<<<G_GRAPHS, 512, 0, stream>>>(gcnt, binned, row_ptr, row_end);

    // h~ = x@W1 (bf16 table) + layer-1 logits + pooled zeroing
    ht_k<<<N_NODES / 64, 256, 0, stream>>>(x, W1, a_src1, a_dst1, hth, als1, ald1, pooled);

    // barrier-free layer-1 aggregation -> h1 fp32
    agg1_k<<<N_NODES / 4, 256, 0, stream>>>(row_ptr, row_end, binned, hth, als1, ald1,
                                            b1, h1);

    // h2 = h1@W2 (bf16) + layer-2 logits
    dense2_k<<<N_NODES / 64, 256, 0, stream>>>(h1, W2, a_src2, a_dst2, h2h, al_s2, al_d2);

    // layer 2 gather (edge-layout shfl form) + fused pooling
    gather2<<<N_NODES / 32, 256, 0, stream>>>(row_ptr, row_end, binned, al_s2, al_d2, h2h,
                                              b2, batch, pooled);

    // head
    head_k<<<1, G_GRAPHS, 0, stream>>>(pooled, clinical, Wc1, bc1, Wc2, bc2, out);
}